// Round 1
// baseline (104.884 us; speedup 1.0000x reference)
//
#include <hip/hip_runtime.h>

typedef __attribute__((ext_vector_type(2))) float f32x2;
typedef __attribute__((ext_vector_type(4))) float f32x4;
typedef __attribute__((ext_vector_type(8))) short s16x8;
typedef __attribute__((ext_vector_type(2))) unsigned int u32x2;
typedef __attribute__((ext_vector_type(4))) unsigned int u32x4;

#define BN 4
#define TN 4096
#define CN 120
#define HN 64

// RNE float->bf16 (finite inputs only)
__device__ __forceinline__ unsigned short f2bf(float f) {
  unsigned int u = __float_as_uint(f);
  unsigned int r = (u + 0x7fffu + ((u >> 16) & 1u)) >> 16;
  return (unsigned short)r;
}
__device__ __forceinline__ float bf2f(unsigned short h) {
  return __uint_as_float((unsigned int)h << 16);
}
__device__ __forceinline__ float fast_exp2(float x) {
#if __has_builtin(__builtin_amdgcn_exp2f)
  return __builtin_amdgcn_exp2f(x);
#else
  return exp2f(x);
#endif
}

// ---------------------------------------------------------------------------
// Workspace layouts (validated r10): K and V stored PRE-PERMUTED into MFMA
// fragment order so every in-loop global load in attn is base + lane*16.
//   Kf[b][kt]   : kt = key/16, 2KB tile. chunk0 byte L*16 = K[b][kt*16 +
//                 (L&15)][h=(L>>4)*8..+8); chunk1 (+1024B) same rows, h+32.
//   Qg[b*T+t][64] rows (bf16, pre-scaled by log2(e)/sqrt(120)).
//   Vf[b][kb32][ht]: 1KB: byte L*16 = V[b][h=ht*16+(L&15)][kb32*32 +
//                 (L>>4)*8..+8).
// ---------------------------------------------------------------------------

// ---------------------------------------------------------------------------
// Kernel 1: projections — unchanged from the 99.2us version (est ~5us, not
// the bottleneck). MFMA engine, x/W split hi/lo bf16 (3 MFMA terms), Q scale
// folded into W pre-split, K=120 zero-padded to 128, grid 768, 4 waves.
// ---------------------------------------------------------------------------
__global__ __launch_bounds__(256, 3) void proj_kernel(
    const float* __restrict__ x, const float* __restrict__ Wk,
    const float* __restrict__ Wq, const float* __restrict__ Wv,
    unsigned short* __restrict__ Kf, unsigned short* __restrict__ Qg,
    unsigned short* __restrict__ Vf) {
  __shared__ struct {
    unsigned short xh[64][136];  // bf16 hi, pitch 136 shorts       17408 B
    unsigned short xl[64][136];  // bf16 lo residual                17408 B
    unsigned short vt[64][72];   // transpose buffer (pitch 72)      9216 B
  } sm;
  const int tid = threadIdx.x;
  const int mat = blockIdx.x >> 8;  // 0=K 1=Q 2=V
  const int rb = blockIdx.x & 255;
  const int row0 = rb * 64;
  const int wave = tid >> 6, lane = tid & 63;
  const int l15 = lane & 15, quad = lane >> 4;
  const int b = row0 >> 12, key0 = row0 & (TN - 1);

  // ---- W B-frags (hi/lo) for this wave's h-tile ----
  const float* Ws = (mat == 0) ? Wk : (mat == 1) ? Wq : Wv;
  const float wsc = (mat == 1) ? 0.13169944f : 1.0f;  // log2(e)/sqrt(120)
  s16x8 wh[4], wl[4];
#pragma unroll
  for (int kc = 0; kc < 4; ++kc) {
#pragma unroll
    for (int j = 0; j < 8; ++j) {
      const int c = kc * 32 + quad * 8 + j;
      const float w = (c < CN) ? Ws[c * HN + wave * 16 + l15] * wsc : 0.f;
      const unsigned short h16 = f2bf(w);
      wh[kc][j] = (short)h16;
      wl[kc][j] = (short)f2bf(w - bf2f(h16));
    }
  }

  // ---- stage x: global f32x4 coalesced, split hi/lo during the copy ----
  for (int n = tid; n < 64 * 30; n += 256) {
    const int row = n / 30, c4 = n - row * 30;
    const f32x4 xv = *(const f32x4*)&x[(size_t)(row0 + row) * CN + c4 * 4];
    u32x2 hp, lp;
#pragma unroll
    for (int e = 0; e < 2; ++e) {
      const unsigned short h0 = f2bf(xv[2 * e]);
      const unsigned short h1 = f2bf(xv[2 * e + 1]);
      hp[e] = (unsigned int)h0 | ((unsigned int)h1 << 16);
      lp[e] = (unsigned int)f2bf(xv[2 * e] - bf2f(h0)) |
              ((unsigned int)f2bf(xv[2 * e + 1] - bf2f(h1)) << 16);
    }
    *(u32x2*)&sm.xh[row][c4 * 4] = hp;
    *(u32x2*)&sm.xl[row][c4 * 4] = lp;
  }
  if (tid < 64) {  // zero-pad c 120..127
    const u32x4 z = {0u, 0u, 0u, 0u};
    *(u32x4*)&sm.xh[tid][120] = z;
    *(u32x4*)&sm.xl[tid][120] = z;
  }
  __syncthreads();

  // ---- MFMA main: 4 m-tiles x 4 k-chunks x 3 split terms ----
  f32x4 acc[4];
#pragma unroll
  for (int mt = 0; mt < 4; ++mt) acc[mt] = 0.f;
#pragma unroll
  for (int mt = 0; mt < 4; ++mt) {
#pragma unroll
    for (int kc = 0; kc < 4; ++kc) {
      const s16x8 ah = *(const s16x8*)&sm.xh[mt * 16 + l15][kc * 32 + quad * 8];
      const s16x8 al = *(const s16x8*)&sm.xl[mt * 16 + l15][kc * 32 + quad * 8];
      acc[mt] = __builtin_amdgcn_mfma_f32_16x16x32_bf16(al, wh[kc], acc[mt], 0, 0, 0);
      acc[mt] = __builtin_amdgcn_mfma_f32_16x16x32_bf16(ah, wl[kc], acc[mt], 0, 0, 0);
      acc[mt] = __builtin_amdgcn_mfma_f32_16x16x32_bf16(ah, wh[kc], acc[mt], 0, 0, 0);
    }
  }

  // ---- epilogue: C-layout -> vt -> global ----
  if (mat < 2) {
    // rows in vt[row][h]
#pragma unroll
    for (int mt = 0; mt < 4; ++mt)
#pragma unroll
      for (int r = 0; r < 4; ++r)
        sm.vt[mt * 16 + quad * 4 + r][wave * 16 + l15] = f2bf(acc[mt][r]);
    __syncthreads();
    if (mat == 1) {
      // Qg rows — each thread owns a 32B quarter-row -> TWO u32x4
      const int row = tid >> 2, seg = tid & 3;
      const u32x4 d0 = *(const u32x4*)&sm.vt[row][seg * 16];
      const u32x4 d1 = *(const u32x4*)&sm.vt[row][seg * 16 + 8];
      unsigned short* qp = &Qg[(size_t)(row0 + row) * HN + seg * 16];
      *(u32x4*)qp = d0;
      *(u32x4*)(qp + 8) = d1;
    } else {
      // Kf frag-ordered tiles (512 chunks, full coverage)
#pragma unroll
      for (int i = 0; i < 2; ++i) {
        const int c = tid + i * 256;  // 512 chunks: 4 kt x 2 ch x 64 L
        const int ktl = c >> 7, ch = (c >> 6) & 1, L = c & 63;
        const u32x4 d =
            *(const u32x4*)&sm.vt[ktl * 16 + (L & 15)][(L >> 4) * 8 + ch * 32];
        *(u32x4*)((unsigned char*)Kf +
                  (((size_t)b * 256 + (key0 >> 4) + ktl) * 128 + ch * 64 + L) *
                      16) = d;
      }
    }
  } else {
    // V transposed in vt[h][row]
#pragma unroll
    for (int mt = 0; mt < 4; ++mt)
#pragma unroll
      for (int r = 0; r < 4; ++r)
        sm.vt[wave * 16 + l15][mt * 16 + quad * 4 + r] = f2bf(acc[mt][r]);
    __syncthreads();
#pragma unroll
    for (int i = 0; i < 2; ++i) {
      const int c = tid + i * 256;  // 512 chunks: 2 kb32 x 4 ht x 64 L
      const int kbl = c >> 8, ht = (c >> 6) & 3, L = c & 63;
      const u32x4 d =
          *(const u32x4*)&sm.vt[ht * 16 + (L & 15)][kbl * 32 + (L >> 4) * 8];
      *(u32x4*)((unsigned char*)Vf +
                (((size_t)b * 128 + (key0 >> 5) + kbl) * 4 + ht) * 1024 +
                L * 16) = d;
    }
  }
}

// ---------------------------------------------------------------------------
// Kernel 2: attention v2 — 64 queries/WAVE (was 32). Rationale: the v1
// kernel moved 512MB through L2 (each wave read its 512-key K/V slab for
// only 32 queries) at ~48% of per-XCD L2 BW with exposed load latency.
// Doubling q/wave halves K/V L2 traffic per MFMA (256MB total) and doubles
// per-wave ILP, compensating the occupancy drop (2048 waves -> 2/SIMD).
// Adds explicit next-iter K prefetch (S-phase loads no longer cold).
// Structure per wave: qf[4][2] (4 q-frags), o[4][4], 512 keys (8 iters),
// same frag layouts / truncation / accumulation semantics as v1.
// Grid: BN*TN/64 = 256 blocks x 512 thr (1 block/CU). Dynamic LDS 73728B
// (p[8 waves][4 qt][16][72] shorts; epilogue union ob[8][64][17]+lb[8][16]).
// ---------------------------------------------------------------------------
__global__ __launch_bounds__(512, 2) void attn_kernel(
    const unsigned short* __restrict__ Qg, const unsigned short* __restrict__ Kf,
    const unsigned short* __restrict__ Vf, float* __restrict__ out) {
  extern __shared__ unsigned char smraw[];
  const int bid = blockIdx.x;                      // [0,256)
  const int xslot = bid & 7;                       // XCD-aware swizzle
  const int b = xslot >> 1;                        // batch -> XCD pair
  const int qt6 = (bid >> 3) | ((xslot & 1) << 5); // [0,64)
  const int qbase = qt6 * 64;
  const int tid = threadIdx.x;
  const int wave = tid >> 6, lane = tid & 63;
  const int l15 = lane & 15, quad = lane >> 4;

  // Q B-operand frags for 4 q-tiles: B[k=h][n=q]: q=l15, h=quad*8+j (+32)
  s16x8 qf[4][2];
#pragma unroll
  for (int qt = 0; qt < 4; ++qt) {
    const unsigned short* qrow =
        Qg + (size_t)(b * TN + qbase + qt * 16 + l15) * HN + quad * 8;
    qf[qt][0] = *(const s16x8*)qrow;
    qf[qt][1] = *(const s16x8*)(qrow + 32);
  }

  const unsigned char* Kfb = (const unsigned char*)Kf + (size_t)b * 524288;
  const unsigned char* Vfb = (const unsigned char*)Vf + (size_t)b * 524288;
  char* pw[4];
#pragma unroll
  for (int qt = 0; qt < 4; ++qt)
    pw[qt] = (char*)smraw + (wave * 4 + qt) * 2304 + l15 * 144;

  f32x4 o[4][4];
#pragma unroll
  for (int qt = 0; qt < 4; ++qt)
#pragma unroll
    for (int t = 0; t < 4; ++t) o[qt][t] = 0.f;
  float lacc[4] = {0.f, 0.f, 0.f, 0.f};

  const int kb0 = wave * 512;  // 8-way key split, 512 keys/wave

  // K-tile register prefetch buffer (4 tiles x 2 chunks = 32 VGPR)
  s16x8 ka[4][2];
#pragma unroll
  for (int t = 0; t < 4; ++t) {
    const unsigned char* ktp = Kfb + (size_t)((kb0 >> 4) + t) * 2048 + lane * 16;
    ka[t][0] = *(const s16x8*)ktp;
    ka[t][1] = *(const s16x8*)(ktp + 1024);
  }

#pragma unroll 1
  for (int it = 0; it < 8; ++it) {
    const int kb = kb0 + it * 64;
    // ---- per 16-key tile t: S MFMAs then IMMEDIATE exp/pack (s dies) ----
#pragma unroll
    for (int t = 0; t < 4; ++t) {
      f32x4 s0 = 0.f, s1 = 0.f, s2 = 0.f, s3 = 0.f;
      s0 = __builtin_amdgcn_mfma_f32_16x16x32_bf16(ka[t][0], qf[0][0], s0, 0, 0, 0);
      s0 = __builtin_amdgcn_mfma_f32_16x16x32_bf16(ka[t][1], qf[0][1], s0, 0, 0, 0);
      s1 = __builtin_amdgcn_mfma_f32_16x16x32_bf16(ka[t][0], qf[1][0], s1, 0, 0, 0);
      s1 = __builtin_amdgcn_mfma_f32_16x16x32_bf16(ka[t][1], qf[1][1], s1, 0, 0, 0);
      s2 = __builtin_amdgcn_mfma_f32_16x16x32_bf16(ka[t][0], qf[2][0], s2, 0, 0, 0);
      s2 = __builtin_amdgcn_mfma_f32_16x16x32_bf16(ka[t][1], qf[2][1], s2, 0, 0, 0);
      s3 = __builtin_amdgcn_mfma_f32_16x16x32_bf16(ka[t][0], qf[3][0], s3, 0, 0, 0);
      s3 = __builtin_amdgcn_mfma_f32_16x16x32_bf16(ka[t][1], qf[3][1], s3, 0, 0, 0);
      // exp2, truncate to bf16, l from truncated values, store P^T.
      // C/D layout: q=l15(col), key = 16t + quad*4 + reg.
#pragma unroll
      for (int qt = 0; qt < 4; ++qt) {
        const f32x4 s = (qt == 0) ? s0 : (qt == 1) ? s1 : (qt == 2) ? s2 : s3;
        unsigned int u0 = __float_as_uint(fast_exp2(fminf(s[0], 80.f)));
        unsigned int u1 = __float_as_uint(fast_exp2(fminf(s[1], 80.f)));
        unsigned int u2 = __float_as_uint(fast_exp2(fminf(s[2], 80.f)));
        unsigned int u3 = __float_as_uint(fast_exp2(fminf(s[3], 80.f)));
        const unsigned int m0 = u0 & 0xffff0000u, m1 = u1 & 0xffff0000u;
        const unsigned int m2 = u2 & 0xffff0000u, m3 = u3 & 0xffff0000u;
        lacc[qt] += (__uint_as_float(m0) + __uint_as_float(m1)) +
                    (__uint_as_float(m2) + __uint_as_float(m3));
        u32x2 w;
        // pack high-halves: w.x = (u0>>16)|(u1&ffff0000) via v_perm_b32
        w.x = __builtin_amdgcn_perm(u1, u0, 0x07060302u);
        w.y = __builtin_amdgcn_perm(u3, u2, 0x07060302u);
        *(u32x2*)(pw[qt] + t * 32 + quad * 8) = w;  // keys 16t+quad*4..+3
      }
    }
    // ---- prefetch next iteration's K tiles (lands under PV phase) ----
    if (it < 7) {
      const int kbn = kb + 64;
#pragma unroll
      for (int t = 0; t < 4; ++t) {
        const unsigned char* ktp =
            Kfb + (size_t)((kbn >> 4) + t) * 2048 + lane * 16;
        ka[t][0] = *(const s16x8*)ktp;
        ka[t][1] = *(const s16x8*)(ktp + 1024);
      }
    }
    // ---- O^T += V * P^T (V frags reused 4x; same-wave LDS RAW) ----
#pragma unroll
    for (int kc = 0; kc < 2; ++kc) {
      const s16x8 pb0 = *(const s16x8*)(pw[0] + quad * 16 + kc * 64);
      const s16x8 pb1 = *(const s16x8*)(pw[1] + quad * 16 + kc * 64);
      const s16x8 pb2 = *(const s16x8*)(pw[2] + quad * 16 + kc * 64);
      const s16x8 pb3 = *(const s16x8*)(pw[3] + quad * 16 + kc * 64);
#pragma unroll
      for (int ht = 0; ht < 4; ++ht) {
        const unsigned char* vtp =
            Vfb + (size_t)((kb >> 5) + kc) * 4096 + ht * 1024 + lane * 16;
        const s16x8 va = *(const s16x8*)vtp;
        o[0][ht] = __builtin_amdgcn_mfma_f32_16x16x32_bf16(va, pb0, o[0][ht], 0, 0, 0);
        o[1][ht] = __builtin_amdgcn_mfma_f32_16x16x32_bf16(va, pb1, o[1][ht], 0, 0, 0);
        o[2][ht] = __builtin_amdgcn_mfma_f32_16x16x32_bf16(va, pb2, o[2][ht], 0, 0, 0);
        o[3][ht] = __builtin_amdgcn_mfma_f32_16x16x32_bf16(va, pb3, o[3][ht], 0, 0, 0);
      }
    }
  }
  // reduce l across quads (lane's column q=l15 fixed across quads)
#pragma unroll
  for (int qt = 0; qt < 4; ++qt) {
    lacc[qt] += __shfl_xor(lacc[qt], 16, 64);
    lacc[qt] += __shfl_xor(lacc[qt], 32, 64);
  }
  __syncthreads();  // all waves done with P slabs before LDS reuse
  // four-phase epilogue, FULLY UNROLLED (literal qt keeps o in VGPRs)
  float* ob = (float*)smraw;                         // [8][64][17]
  float* lb = (float*)(smraw + 8 * 64 * 17 * 4);     // [8][16]
#pragma unroll
  for (int qt = 0; qt < 4; ++qt) {
    if (lane < 16) lb[wave * 16 + l15] = lacc[qt];
#pragma unroll
    for (int ht = 0; ht < 4; ++ht)
#pragma unroll
      for (int r = 0; r < 4; ++r)
        ob[(wave * 64 + ht * 16 + quad * 4 + r) * 17 + l15] = o[qt][ht][r];
    __syncthreads();
    const int h = tid & 63;
    const int wq = tid >> 6;  // 0..7
#pragma unroll
    for (int i = 0; i < 2; ++i) {
      const int qq = (i << 3) | wq;  // 0..15
      float ssum = 0.f, ll = 0.f;
#pragma unroll
      for (int w = 0; w < 8; ++w) {
        ssum += ob[(w * 64 + h) * 17 + qq];
        ll += lb[w * 16 + qq];
      }
      out[(size_t)(b * TN + qbase + qt * 16 + qq) * HN + h] = ssum / ll;
    }
    __syncthreads();  // phase qt's reads done before phase qt+1 overwrites
  }
}

extern "C" void kernel_launch(void* const* d_in, const int* in_sizes, int n_in,
                              void* d_out, int out_size, void* d_ws,
                              size_t ws_size, hipStream_t stream) {
  const float* x = (const float*)d_in[0];
  const float* Wk = (const float*)d_in[1];
  const float* Wq = (const float*)d_in[2];
  const float* Wv = (const float*)d_in[3];
  unsigned short* Kf = (unsigned short*)d_ws;             // [B][256] 2KB tiles
  unsigned short* Qg = Kf + (size_t)BN * TN * HN;         // [B*T][64] rows
  unsigned short* Vf = Qg + (size_t)BN * TN * HN;         // [B][128][4] 1KB
  float* out = (float*)d_out;
  static bool smset = false;
  if (!smset) {
    (void)hipFuncSetAttribute((const void*)attn_kernel,
                              hipFuncAttributeMaxDynamicSharedMemorySize,
                              73728);
    smset = true;
  }
  proj_kernel<<<768, 256, 0, stream>>>(x, Wk, Wq, Wv, Kf, Qg, Vf);
  attn_kernel<<<BN * TN / 64, 512, 73728, stream>>>(Qg, Kf, Vf, out);
}